// Round 8
// baseline (910.700 us; speedup 1.0000x reference)
//
#include <hip/hip_runtime.h>
#include <hip/hip_fp16.h>

#define NN 64000
#define ET 1024000
#define HALF_N 32000

typedef __attribute__((ext_vector_type(8))) short short8;
typedef __attribute__((ext_vector_type(8))) _Float16 half8;
typedef __attribute__((ext_vector_type(4))) float f32x4;

__device__ inline float h2f(__half h) { return __half2float(h); }
__device__ inline float dec_w(unsigned p) {
  return __half2float(__ushort_as_half((unsigned short)(p >> 16)));
}

// ---------------- graph build (two-region CSR: src<32000 | src>=32000) ----

__global__ void k_deg2(const int* __restrict__ ei, int* __restrict__ deg2) {
  int e = blockIdx.x * 256 + threadIdx.x;
  if (e < ET) {
    int s = ei[e], d = ei[ET + e];
    atomicAdd(&deg2[d + (s >= HALF_N ? NN : 0)], 1);
  }
}

// scan over 128000 entries: 500 blocks x 256
__global__ void k_scan1(const int* __restrict__ deg2, int* __restrict__ rowp2,
                        int* __restrict__ bsum) {
  __shared__ int buf[256];
  int t = threadIdx.x;
  int idx = blockIdx.x * 256 + t;
  int v = deg2[idx];
  buf[t] = v;
  __syncthreads();
  for (int off = 1; off < 256; off <<= 1) {
    int x = (t >= off) ? buf[t - off] : 0;
    __syncthreads();
    buf[t] += x;
    __syncthreads();
  }
  rowp2[idx] = buf[t] - v;
  if (t == 255) bsum[blockIdx.x] = buf[t];
}

__global__ __launch_bounds__(512) void k_scan2(const int* __restrict__ bsum,
                                               int* __restrict__ boff) {
  __shared__ int buf[512];
  int t = threadIdx.x;
  int v = (t < 500) ? bsum[t] : 0;
  buf[t] = v;
  __syncthreads();
  for (int off = 1; off < 512; off <<= 1) {
    int x = (t >= off) ? buf[t - off] : 0;
    __syncthreads();
    buf[t] += x;
    __syncthreads();
  }
  if (t < 500) boff[t] = buf[t] - v;
}

__global__ void k_scan3(int* __restrict__ rowp2, const int* __restrict__ boff,
                        int* __restrict__ fillp2, const int* __restrict__ deg2,
                        float* __restrict__ dis) {
  int idx = blockIdx.x * 256 + threadIdx.x;
  int v = rowp2[idx] + boff[blockIdx.x];
  rowp2[idx] = v;
  fillp2[idx] = v;
  if (idx < NN) {
    int total = deg2[idx] + deg2[idx + NN];
    dis[idx] = total > 0 ? rsqrtf((float)total) : 0.f;
  }
  if (idx == 0) rowp2[2 * NN] = ET;
}

// packed edge record: low16 = src node, high16 = f16 norm
__global__ void k_fill(const int* __restrict__ ei, const float* __restrict__ dis,
                       int* __restrict__ fillp2, unsigned* __restrict__ edata) {
  int e = blockIdx.x * 256 + threadIdx.x;
  if (e >= ET) return;
  int s = ei[e];
  int d = ei[ET + e];
  float nrm = -dis[s] * dis[d];
  unsigned packed = (unsigned)s |
      ((unsigned)__half_as_ushort(__float2half(nrm)) << 16);
  int p = atomicAdd(&fillp2[d + (s >= HALF_N ? NN : 0)], 1);
  edata[p] = packed;
}

// ---------------- Chebyshev weight fold ----------------
// out = h*W0 + T1*W1 + (2*L*T1 - h)*W2 == h*(W0-W2) + T1*W1 + (L*T1)*(2*W2)

struct WXArgs {
  const float *s0, *s1, *s2, *s3, *s4, *s5;
  float *d0, *d1, *d2, *d3, *d4, *d5;
};

__global__ void k_wx(WXArgs a) {
  int b = blockIdx.x;
  int set = b >> 4;
  const float* s;
  float* d;
  int n = (set < 5) ? 4096 : 64;
  switch (set) {
    case 0: s = a.s0; d = a.d0; break;
    case 1: s = a.s1; d = a.d1; break;
    case 2: s = a.s2; d = a.d2; break;
    case 3: s = a.s3; d = a.d3; break;
    case 4: s = a.s4; d = a.d4; break;
    default: s = a.s5; d = a.d5; break;
  }
  int i = (set < 5) ? (b - set * 16) * 256 + threadIdx.x : threadIdx.x;
  if (i < n) {
    d[i]         = s[i] - s[i + 2 * n];
    d[i + n]     = s[i + n];
    d[i + 2 * n] = 2.f * s[i + 2 * n];
  }
}

// ---------------- scalar (1-channel) plain prop for layer 1 (f32) ----------
// x is 256 KB -> trivially cached; do both CSR halves in one kernel.

__global__ void k_prop_s(const float* __restrict__ in, const int* __restrict__ rowp2,
                         const unsigned* __restrict__ edata, float* __restrict__ out) {
  int n = blockIdx.x * 256 + threadIdx.x;
  if (n >= NN) return;
  float acc = 0.f;
#pragma unroll
  for (int hh = 0; hh < 2; ++hh) {
    int s = rowp2[hh * NN + n], e = rowp2[hh * NN + n + 1];
    int j = s;
    for (; j + 4 <= e; j += 4) {
      unsigned e0 = edata[j], e1 = edata[j + 1], e2 = edata[j + 2], e3 = edata[j + 3];
      acc += in[e0 & 0xFFFFu] * dec_w(e0) + in[e1 & 0xFFFFu] * dec_w(e1) +
             in[e2 & 0xFFFFu] * dec_w(e2) + in[e3 & 0xFFFFu] * dec_w(e3);
    }
    for (; j < e; ++j) {
      unsigned e0 = edata[j];
      acc += in[e0 & 0xFFFFu] * dec_w(e0);
    }
  }
  out[n] = acc;
}

__global__ void k_layer1(const float* __restrict__ x, const float* __restrict__ t1,
                         const float* __restrict__ g2, const float* __restrict__ w,
                         const float* __restrict__ b, __half* __restrict__ out) {
  int t = threadIdx.x;
  int node = blockIdx.x * 4 + (t >> 6);
  int f = t & 63;
  float v = x[node] * w[f] + t1[node] * w[64 + f] + g2[node] * w[128 + f] + b[f];
  out[(size_t)node * 64 + f] = __float2half(fmaxf(v, 0.f));
}

// ---------------- 64-ch prop pass: wave per node, lane = feature -----------
// One pass gathers only from a 3.9 MiB source window (L2-resident per XCD).
// FINAL=0: write fp16 partial (nt). FINAL=1: add partial, write out (nt).

template<int FINAL>
__global__ __launch_bounds__(256) void k_prop64p(const __half* __restrict__ in,
    const int* __restrict__ rowp, const unsigned* __restrict__ edata,
    const __half* __restrict__ accin, __half* __restrict__ out) {
  int node = __builtin_amdgcn_readfirstlane(blockIdx.x * 4 + (threadIdx.x >> 6));
  int f = threadIdx.x & 63;
  int s = rowp[node], e = rowp[node + 1];
  float a[16];
#pragma unroll
  for (int i = 0; i < 16; ++i) a[i] = 0.f;
  int j = s;
  for (; j + 16 <= e; j += 16) {
    unsigned ed[16];
#pragma unroll
    for (int i = 0; i < 16; ++i) ed[i] = edata[j + i];
    float v[16];
#pragma unroll
    for (int i = 0; i < 16; ++i) v[i] = h2f(in[(size_t)(ed[i] & 0xFFFFu) * 64 + f]);
#pragma unroll
    for (int i = 0; i < 16; ++i) a[i] += v[i] * dec_w(ed[i]);
  }
  for (; j + 8 <= e; j += 8) {
    unsigned ed[8];
#pragma unroll
    for (int i = 0; i < 8; ++i) ed[i] = edata[j + i];
    float v[8];
#pragma unroll
    for (int i = 0; i < 8; ++i) v[i] = h2f(in[(size_t)(ed[i] & 0xFFFFu) * 64 + f]);
#pragma unroll
    for (int i = 0; i < 8; ++i) a[i] += v[i] * dec_w(ed[i]);
  }
  for (; j + 4 <= e; j += 4) {
    unsigned ed[4];
#pragma unroll
    for (int i = 0; i < 4; ++i) ed[i] = edata[j + i];
    float v[4];
#pragma unroll
    for (int i = 0; i < 4; ++i) v[i] = h2f(in[(size_t)(ed[i] & 0xFFFFu) * 64 + f]);
#pragma unroll
    for (int i = 0; i < 4; ++i) a[i] += v[i] * dec_w(ed[i]);
  }
  for (; j < e; ++j) {
    unsigned e0 = edata[j];
    a[0] += h2f(in[(size_t)(e0 & 0xFFFFu) * 64 + f]) * dec_w(e0);
  }
#pragma unroll
  for (int i = 0; i < 8; ++i) a[i] += a[i + 8];
#pragma unroll
  for (int i = 0; i < 4; ++i) a[i] += a[i + 4];
  float acc = (a[0] + a[1]) + (a[2] + a[3]);
  size_t o = (size_t)node * 64 + f;
  if (FINAL) {
    unsigned short pv = __builtin_nontemporal_load((const unsigned short*)accin + o);
    acc += __half2float(__ushort_as_half(pv));
  }
  unsigned short us = __half_as_ushort(__float2half(acc));
  __builtin_nontemporal_store(us, (unsigned short*)out + o);
}

// ------- fused cheb matmul: out = T0@W0' + T1@W1' + G2@W2' (+b, relu/res), f16 IO

template<int RELU, int RES>
__global__ __launch_bounds__(256) void k_mat64(
    const __half* __restrict__ T0, const __half* __restrict__ T1,
    const __half* __restrict__ T2, const float* __restrict__ W,
    const float* __restrict__ bias, const __half* __restrict__ res,
    __half* __restrict__ out) {
  __shared__ float Ws[3 * 64 * 64];
  __shared__ float As[256 * 21];
  int t = threadIdx.x;
  int node0 = blockIdx.x * 256;
  {
    const float4* Wv = (const float4*)W;
    float4* Sv = (float4*)Ws;
    for (int i = t; i < 3072; i += 256) Sv[i] = Wv[i];
  }
  int fi = t & 7;
  int ni = t >> 3;
  float acc[8][8];
#pragma unroll
  for (int j = 0; j < 8; ++j)
#pragma unroll
    for (int m = 0; m < 8; ++m) acc[j][m] = 0.f;

  for (int p = 0; p < 12; ++p) {
    int k = p >> 2, c0 = (p & 3) << 4;
    const __half* Tsel = (k == 0) ? T0 : (k == 1) ? T1 : T2;
    const __half* src = Tsel + (size_t)(node0 + t) * 64 + c0;
    short8 r0 = *(const short8*)(src);
    short8 r1 = *(const short8*)(src + 8);
    __syncthreads();
    float* dst = &As[t * 21];
#pragma unroll
    for (int i = 0; i < 8; ++i) dst[i] = h2f(__ushort_as_half((unsigned short)r0[i]));
#pragma unroll
    for (int i = 0; i < 8; ++i) dst[8 + i] = h2f(__ushort_as_half((unsigned short)r1[i]));
    __syncthreads();
#pragma unroll
    for (int cc = 0; cc < 16; ++cc) {
      int c = c0 + cc;
      float a[8], bb[8];
#pragma unroll
      for (int j = 0; j < 8; ++j) a[j] = As[(ni + 32 * j) * 21 + cc];
      const float* wrow = &Ws[k * 4096 + c * 64];
#pragma unroll
      for (int m = 0; m < 8; ++m) bb[m] = wrow[fi + 8 * m];
#pragma unroll
      for (int j = 0; j < 8; ++j)
#pragma unroll
        for (int m = 0; m < 8; ++m) acc[j][m] += a[j] * bb[m];
    }
  }
#pragma unroll
  for (int j = 0; j < 8; ++j) {
    int node = node0 + ni + 32 * j;
#pragma unroll
    for (int m = 0; m < 8; ++m) {
      int f = fi + 8 * m;
      float v = acc[j][m] + bias[f];
      if (RES) v += h2f(res[(size_t)node * 64 + f]);
      if (RELU) v = fmaxf(v, 0.f);
      out[(size_t)node * 64 + f] = __float2half(v);
    }
  }
}

// ---------------- readout (MFMA lin1, unchanged from round 7) --------------

__global__ __launch_bounds__(256) void k_lin1(const __half* __restrict__ H,
    const float* __restrict__ W, float* __restrict__ r1p) {
  __shared__ _Float16 Hs[64][264];
  int t = threadIdx.x;
  int bo = blockIdx.x & 7;
  int bk = blockIdx.x >> 3;      // 0..249
  int kb = bk * 256;
  {
    int g = t >> 2, ks = (t & 3) * 64;
    const short8* src = (const short8*)(H + (size_t)g * 64000 + kb + ks);
#pragma unroll
    for (int i = 0; i < 8; ++i) {
      short8 v = src[i];
      *(short8*)&Hs[g][ks + i * 8] = v;
    }
  }
  __syncthreads();

  int wv = t >> 6, lane = t & 63;
  int arow = lane & 15, kgrp = (lane >> 4) * 8;
  f32x4 acc0 = {0.f, 0.f, 0.f, 0.f};
  f32x4 acc1 = {0.f, 0.f, 0.f, 0.f};
  f32x4 acc2 = {0.f, 0.f, 0.f, 0.f};
  f32x4 acc3 = {0.f, 0.f, 0.f, 0.f};

  const float* wp = W + (size_t)(bo * 64 + wv * 16 + arow) * 64000 + kb + kgrp;
#pragma unroll
  for (int kstep = 0; kstep < 8; ++kstep) {
    f32x4 w0 = *(const f32x4*)(wp);
    f32x4 w1 = *(const f32x4*)(wp + 4);
    wp += 32;
    half8 a;
    a[0] = (_Float16)w0[0]; a[1] = (_Float16)w0[1];
    a[2] = (_Float16)w0[2]; a[3] = (_Float16)w0[3];
    a[4] = (_Float16)w1[0]; a[5] = (_Float16)w1[1];
    a[6] = (_Float16)w1[2]; a[7] = (_Float16)w1[3];
    int kk = kstep * 32 + kgrp;
    half8 b0 = *(const half8*)&Hs[arow][kk];
    half8 b1 = *(const half8*)&Hs[16 + arow][kk];
    half8 b2 = *(const half8*)&Hs[32 + arow][kk];
    half8 b3 = *(const half8*)&Hs[48 + arow][kk];
    acc0 = __builtin_amdgcn_mfma_f32_16x16x32_f16(a, b0, acc0, 0, 0, 0);
    acc1 = __builtin_amdgcn_mfma_f32_16x16x32_f16(a, b1, acc1, 0, 0, 0);
    acc2 = __builtin_amdgcn_mfma_f32_16x16x32_f16(a, b2, acc2, 0, 0, 0);
    acc3 = __builtin_amdgcn_mfma_f32_16x16x32_f16(a, b3, acc3, 0, 0, 0);
  }

  float* dst = r1p + (size_t)bk * 32768;
  int orow = bo * 64 + wv * 16 + (lane >> 4) * 4;
  int g = lane & 15;
#pragma unroll
  for (int reg = 0; reg < 4; ++reg) {
    dst[(orow + reg) * 64 + g]      = acc0[reg];
    dst[(orow + reg) * 64 + 16 + g] = acc1[reg];
    dst[(orow + reg) * 64 + 32 + g] = acc2[reg];
    dst[(orow + reg) * 64 + 48 + g] = acc3[reg];
  }
}

// reduce 250 partials, add bias, relu -> r1t[o][g]
__global__ void k_red(const float* __restrict__ r1p, const float* __restrict__ b,
                      float* __restrict__ r1t) {
  int i = blockIdx.x * 256 + threadIdx.x;  // 0..32767
  float s = 0.f;
#pragma unroll 5
  for (int p = 0; p < 250; ++p) s += r1p[(size_t)p * 32768 + i];
  int o = i >> 6;
  r1t[i] = fmaxf(s + b[o], 0.f);
}

__global__ void k_lin2(const float* __restrict__ r1t, const float* __restrict__ W,
                       const float* __restrict__ b, float* __restrict__ r2t) {
  int o = blockIdx.x, g = threadIdx.x;
  float acc = 0.f;
#pragma unroll 4
  for (int i = 0; i < 512; ++i) acc += r1t[i * 64 + g] * W[o * 512 + i];
  r2t[o * 64 + g] = fmaxf(acc + b[o], 0.f);
}

__global__ void k_lin3(const float* __restrict__ r2t, const float* __restrict__ W,
                       const float* __restrict__ b, float* __restrict__ out) {
  int o = blockIdx.x, g = threadIdx.x;
  float acc = 0.f;
#pragma unroll 4
  for (int i = 0; i < 512; ++i) acc += r2t[i * 64 + g] * W[o * 512 + i];
  out[g * 10 + o] = fmaxf(acc + b[o], 0.f);
}

// ---------------- launch ----------------

extern "C" void kernel_launch(void* const* d_in, const int* in_sizes, int n_in,
                              void* d_out, int out_size, void* d_ws, size_t ws_size,
                              hipStream_t stream) {
  const float* x    = (const float*)d_in[0];
  const int*   ei   = (const int*)d_in[1];
  const float* w1_1 = (const float*)d_in[3];  const float* b1_1 = (const float*)d_in[4];
  const float* w1_2 = (const float*)d_in[5];  const float* b1_2 = (const float*)d_in[6];
  const float* w1_3 = (const float*)d_in[7];  const float* b1_3 = (const float*)d_in[8];
  const float* w2_1 = (const float*)d_in[9];  const float* b2_1 = (const float*)d_in[10];
  const float* w2_2 = (const float*)d_in[11]; const float* b2_2 = (const float*)d_in[12];
  const float* w3_1 = (const float*)d_in[13]; const float* b3_1 = (const float*)d_in[14];
  const float* l1w  = (const float*)d_in[15]; const float* l1b  = (const float*)d_in[16];
  const float* l2w  = (const float*)d_in[17]; const float* l2b  = (const float*)d_in[18];
  const float* l3w  = (const float*)d_in[19]; const float* l3b  = (const float*)d_in[20];

  char* ws = (char*)d_ws;
  size_t off = 0;
  auto alloc = [&](size_t bytes) -> char* {
    char* p = ws + off;
    off += (bytes + 255) & ~(size_t)255;
    return p;
  };
  __half* A    = (__half*)alloc((size_t)NN * 64 * 2);
  __half* Bb   = (__half*)alloc((size_t)NN * 64 * 2);
  __half* C    = (__half*)alloc((size_t)NN * 64 * 2);
  __half* T1   = (__half*)alloc((size_t)NN * 64 * 2);
  __half* T2   = (__half*)alloc((size_t)NN * 64 * 2);
  __half* P16  = (__half*)alloc((size_t)NN * 64 * 2);   // pass-A partial
  int*   deg2 = (int*)alloc(2 * NN * 4);
  float* dis  = (float*)alloc(NN * 4);
  int*   rowp2= (int*)alloc((2 * NN + 1) * 4);
  int*   fillp2=(int*)alloc(2 * NN * 4);
  unsigned* edata = (unsigned*)alloc((size_t)ET * 4);
  float* t1s  = (float*)alloc(NN * 4);
  float* g2s  = (float*)alloc(NN * 4);
  float* r1t  = (float*)alloc(512 * 64 * 4);
  float* r2t  = (float*)alloc(512 * 64 * 4);
  int*   bsum = (int*)alloc(512 * 4);
  int*   boff = (int*)alloc(512 * 4);
  float* r1p  = (float*)alloc((size_t)250 * 32768 * 4);
  float* wt11 = (float*)alloc(192 * 4);
  float* wt12 = (float*)alloc(12288 * 4);
  float* wt13 = (float*)alloc(12288 * 4);
  float* wt21 = (float*)alloc(12288 * 4);
  float* wt22 = (float*)alloc(12288 * 4);
  float* wt31 = (float*)alloc(12288 * 4);

  hipMemsetAsync(deg2, 0, 2 * NN * 4, stream);

  k_deg2<<<ET / 256, 256, 0, stream>>>(ei, deg2);
  k_scan1<<<2 * NN / 256, 256, 0, stream>>>(deg2, rowp2, bsum);
  k_scan2<<<1, 512, 0, stream>>>(bsum, boff);
  k_scan3<<<2 * NN / 256, 256, 0, stream>>>(rowp2, boff, fillp2, deg2, dis);
  k_fill<<<ET / 256, 256, 0, stream>>>(ei, dis, fillp2, edata);

  WXArgs wx{w1_2, w1_3, w2_1, w2_2, w3_1, w1_1,
            wt12, wt13, wt21, wt22, wt31, wt11};
  k_wx<<<81, 256, 0, stream>>>(wx);

  // layer 1 (1 -> 64 channels)
  k_prop_s<<<NN / 256, 256, 0, stream>>>(x, rowp2, edata, t1s);
  k_prop_s<<<NN / 256, 256, 0, stream>>>(t1s, rowp2, edata, g2s);
  k_layer1<<<NN / 4, 256, 0, stream>>>(x, t1s, g2s, wt11, b1_1, A);

  auto prop = [&](const __half* in, __half* out) {
    k_prop64p<0><<<NN / 4, 256, 0, stream>>>(in, rowp2, edata, nullptr, P16);
    k_prop64p<1><<<NN / 4, 256, 0, stream>>>(in, rowp2 + NN, edata, P16, out);
  };
  auto cheb = [&](const __half* in, const float* Wt, const float* bias,
                  int relu_f, const __half* res, __half* out) {
    prop(in, T1);
    prop(T1, T2);
    if (relu_f)
      k_mat64<1, 0><<<NN / 256, 256, 0, stream>>>(in, T1, T2, Wt, bias, nullptr, out);
    else
      k_mat64<0, 1><<<NN / 256, 256, 0, stream>>>(in, T1, T2, Wt, bias, res, out);
  };

  cheb(A,  wt12, b1_2, 1, nullptr, Bb);
  cheb(Bb, wt13, b1_3, 0, A,       C);
  cheb(C,  wt21, b2_1, 1, nullptr, A);
  cheb(A,  wt22, b2_2, 0, C,       Bb);
  cheb(Bb, wt31, b3_1, 1, nullptr, C);   // final H in C

  k_lin1<<<2000, 256, 0, stream>>>(C, l1w, r1p);
  k_red<<<32768 / 256, 256, 0, stream>>>(r1p, l1b, r1t);
  k_lin2<<<512, 64, 0, stream>>>(r1t, l2w, l2b, r2t);
  k_lin3<<<10, 64, 0, stream>>>(r2t, l3w, l3b, (float*)d_out);
}

// Round 9
// 816.013 us; speedup vs baseline: 1.1160x; 1.1160x over previous
//
#include <hip/hip_runtime.h>
#include <hip/hip_fp16.h>

#define NN 64000
#define ET 1024000

typedef __attribute__((ext_vector_type(8))) short short8;
typedef __attribute__((ext_vector_type(8))) _Float16 half8;
typedef __attribute__((ext_vector_type(4))) float f32x4;

__device__ inline float h2f(__half h) { return __half2float(h); }
__device__ inline float dec_w(unsigned p) {
  return __half2float(__ushort_as_half((unsigned short)(p >> 16)));
}

// ---------------- graph build (r7 single-region CSR) ----------------

__global__ void k_deg(const int* __restrict__ ei, int* __restrict__ deg) {
  int e = blockIdx.x * 256 + threadIdx.x;
  if (e < ET) atomicAdd(&deg[ei[e]], 1);
}

__global__ void k_scan1(const int* __restrict__ deg, float* __restrict__ dis,
                        int* __restrict__ rowp, int* __restrict__ bsum) {
  __shared__ int buf[256];
  int t = threadIdx.x;
  int idx = blockIdx.x * 256 + t;
  int v = deg[idx];
  dis[idx] = v > 0 ? rsqrtf((float)v) : 0.f;
  buf[t] = v;
  __syncthreads();
  for (int off = 1; off < 256; off <<= 1) {
    int x = (t >= off) ? buf[t - off] : 0;
    __syncthreads();
    buf[t] += x;
    __syncthreads();
  }
  rowp[idx] = buf[t] - v;
  if (t == 255) bsum[blockIdx.x] = buf[t];
}

__global__ void k_scan2(const int* __restrict__ bsum, int* __restrict__ boff) {
  __shared__ int buf[256];
  int t = threadIdx.x;
  int v = (t < 250) ? bsum[t] : 0;
  buf[t] = v;
  __syncthreads();
  for (int off = 1; off < 256; off <<= 1) {
    int x = (t >= off) ? buf[t - off] : 0;
    __syncthreads();
    buf[t] += x;
    __syncthreads();
  }
  if (t < 250) boff[t] = buf[t] - v;
}

__global__ void k_scan3(int* __restrict__ rowp, const int* __restrict__ boff,
                        int* __restrict__ fillp) {
  int idx = blockIdx.x * 256 + threadIdx.x;
  int v = rowp[idx] + boff[blockIdx.x];
  rowp[idx] = v;
  fillp[idx] = v;
  if (idx == 0) rowp[NN] = ET;
}

// packed edge record: low16 = src node, high16 = f16 norm
__global__ void k_fill(const int* __restrict__ ei, const float* __restrict__ dis,
                       int* __restrict__ fillp, unsigned* __restrict__ edata) {
  int e = blockIdx.x * 256 + threadIdx.x;
  if (e >= ET) return;
  int s = ei[e];
  int d = ei[ET + e];
  float nrm = -dis[s] * dis[d];
  unsigned packed = (unsigned)s |
      ((unsigned)__half_as_ushort(__float2half(nrm)) << 16);
  int p = atomicAdd(&fillp[d], 1);
  edata[p] = packed;
}

// ---------------- Chebyshev weight fold ----------------
// out = h*W0 + T1*W1 + (2*L*T1 - h)*W2 == h*(W0-W2) + T1*W1 + (L*T1)*(2*W2)

// layer-1 weights [3][1][64] -> folded f32
__global__ void k_wx1(const float* __restrict__ s, float* __restrict__ d) {
  int f = threadIdx.x;  // 64
  d[f]       = s[f] - s[128 + f];
  d[64 + f]  = s[64 + f];
  d[128 + f] = 2.f * s[128 + f];
}

// [3][64k][64f] -> folded fp16 TRANSPOSED [3][64f][64k]
__global__ void k_wxt(const float* __restrict__ s, __half* __restrict__ d) {
  int i = blockIdx.x * 256 + threadIdx.x;   // 0..12287
  int arr = i >> 12, rem = i & 4095, f = rem >> 6, k = rem & 63;
  float s0 = s[k * 64 + f];
  float s1 = s[4096 + k * 64 + f];
  float s2 = s[8192 + k * 64 + f];
  float v = arr == 0 ? s0 - s2 : (arr == 1 ? s1 : 2.f * s2);
  d[i] = __float2half(v);
}

// ---------------- scalar (1-channel) plain prop for layer 1 (f32) ----------

__global__ void k_prop_s(const float* __restrict__ in, const int* __restrict__ rowp,
                         const unsigned* __restrict__ edata, float* __restrict__ out) {
  int n = blockIdx.x * 256 + threadIdx.x;
  if (n >= NN) return;
  int s = rowp[n], e = rowp[n + 1];
  float acc = 0.f;
  int j = s;
  for (; j + 4 <= e; j += 4) {
    unsigned e0 = edata[j], e1 = edata[j + 1], e2 = edata[j + 2], e3 = edata[j + 3];
    acc += in[e0 & 0xFFFFu] * dec_w(e0) + in[e1 & 0xFFFFu] * dec_w(e1) +
           in[e2 & 0xFFFFu] * dec_w(e2) + in[e3 & 0xFFFFu] * dec_w(e3);
  }
  for (; j < e; ++j) {
    unsigned e0 = edata[j];
    acc += in[e0 & 0xFFFFu] * dec_w(e0);
  }
  out[n] = acc;
}

__global__ void k_layer1(const float* __restrict__ x, const float* __restrict__ t1,
                         const float* __restrict__ g2, const float* __restrict__ w,
                         const float* __restrict__ b, __half* __restrict__ out) {
  int t = threadIdx.x;
  int node = blockIdx.x * 4 + (t >> 6);
  int f = t & 63;
  float v = x[node] * w[f] + t1[node] * w[64 + f] + g2[node] * w[128 + f] + b[f];
  out[(size_t)node * 64 + f] = __float2half(fmaxf(v, 0.f));
}

// ---------------- 64-ch prop: EDGE-PARALLEL, 2 waves per node -------------
// Block = 4 waves = 2 nodes x 2 edge-halves. Each wave gathers its half
// (8-deep ladder), halves combine via LDS. Doubles wave concurrency.

__global__ __launch_bounds__(256) void k_prop64(const __half* __restrict__ in,
    const int* __restrict__ rowp, const unsigned* __restrict__ edata,
    __half* __restrict__ out) {
  __shared__ float part[2][64];
  int wid = threadIdx.x >> 6;
  int nodeSel = wid >> 1;
  int half = wid & 1;
  int node = __builtin_amdgcn_readfirstlane(blockIdx.x * 2 + nodeSel);
  int f = threadIdx.x & 63;
  int s0 = rowp[node], e0 = rowp[node + 1];
  int mid = (s0 + e0) >> 1;
  int s = half ? mid : s0;
  int e = half ? e0 : mid;
  float a[8];
#pragma unroll
  for (int i = 0; i < 8; ++i) a[i] = 0.f;
  int j = s;
  for (; j + 8 <= e; j += 8) {
    unsigned ed[8];
#pragma unroll
    for (int i = 0; i < 8; ++i) ed[i] = edata[j + i];
    float v[8];
#pragma unroll
    for (int i = 0; i < 8; ++i) v[i] = h2f(in[(size_t)(ed[i] & 0xFFFFu) * 64 + f]);
#pragma unroll
    for (int i = 0; i < 8; ++i) a[i] += v[i] * dec_w(ed[i]);
  }
  for (; j + 4 <= e; j += 4) {
    unsigned ed[4];
#pragma unroll
    for (int i = 0; i < 4; ++i) ed[i] = edata[j + i];
    float v[4];
#pragma unroll
    for (int i = 0; i < 4; ++i) v[i] = h2f(in[(size_t)(ed[i] & 0xFFFFu) * 64 + f]);
#pragma unroll
    for (int i = 0; i < 4; ++i) a[i] += v[i] * dec_w(ed[i]);
  }
  for (; j < e; ++j) {
    unsigned e0r = edata[j];
    a[0] += h2f(in[(size_t)(e0r & 0xFFFFu) * 64 + f]) * dec_w(e0r);
  }
#pragma unroll
  for (int i = 0; i < 4; ++i) a[i] += a[i + 4];
  float acc = (a[0] + a[1]) + (a[2] + a[3]);
  if (half == 0) part[nodeSel][f] = acc;
  __syncthreads();
  if (half == 1) {
    acc += part[nodeSel][f];
    out[(size_t)node * 64 + f] = __float2half(acc);
  }
}

// ------- fused cheb matmul via MFMA: out = [T0|T1|G2] @ Wcat' (+b, relu/res)
// A = T rows (node = lane&15, 8 contig k), B = wtT rows (f = lane&15, same k),
// D: col = f, row = node (validated pattern from lin1).

template<int RELU, int RES>
__global__ __launch_bounds__(256) void k_mat64(
    const __half* __restrict__ T0, const __half* __restrict__ T1,
    const __half* __restrict__ T2, const __half* __restrict__ wtT,  // [3][64f][64k]
    const float* __restrict__ bias, const __half* __restrict__ res,
    __half* __restrict__ out) {
  int t = threadIdx.x;
  int wv = t >> 6, lane = t & 63;
  int node0 = blockIdx.x * 256 + wv * 64;
  int l15 = lane & 15, kg = (lane >> 4) * 8;
  f32x4 acc[4][4];
#pragma unroll
  for (int mt = 0; mt < 4; ++mt)
#pragma unroll
    for (int nt = 0; nt < 4; ++nt) acc[mt][nt] = {0.f, 0.f, 0.f, 0.f};

  const __half* Ts[3] = {T0, T1, T2};
#pragma unroll
  for (int arr = 0; arr < 3; ++arr) {
    const __half* T = Ts[arr];
    const __half* wb = wtT + arr * 4096;
#pragma unroll
    for (int ks = 0; ks < 2; ++ks) {
      int k0 = ks * 32 + kg;
      half8 b[4];
#pragma unroll
      for (int nt = 0; nt < 4; ++nt)
        b[nt] = *(const half8*)&wb[(nt * 16 + l15) * 64 + k0];
#pragma unroll
      for (int mt = 0; mt < 4; ++mt) {
        half8 a = *(const half8*)&T[(size_t)(node0 + mt * 16 + l15) * 64 + k0];
#pragma unroll
        for (int nt = 0; nt < 4; ++nt)
          acc[mt][nt] = __builtin_amdgcn_mfma_f32_16x16x32_f16(a, b[nt], acc[mt][nt], 0, 0, 0);
      }
    }
  }

  int row0 = (lane >> 4) * 4;
#pragma unroll
  for (int mt = 0; mt < 4; ++mt) {
#pragma unroll
    for (int nt = 0; nt < 4; ++nt) {
      int fcol = nt * 16 + l15;
      float bv = bias[fcol];
#pragma unroll
      for (int reg = 0; reg < 4; ++reg) {
        int node = node0 + mt * 16 + row0 + reg;
        float v = acc[mt][nt][reg] + bv;
        if (RES) v += h2f(res[(size_t)node * 64 + fcol]);
        if (RELU) v = fmaxf(v, 0.f);
        out[(size_t)node * 64 + fcol] = __float2half(v);
      }
    }
  }
}

// ---------------- readout (MFMA lin1, unchanged from round 7) --------------

__global__ __launch_bounds__(256) void k_lin1(const __half* __restrict__ H,
    const float* __restrict__ W, float* __restrict__ r1p) {
  __shared__ _Float16 Hs[64][264];
  int t = threadIdx.x;
  int bo = blockIdx.x & 7;
  int bk = blockIdx.x >> 3;      // 0..249
  int kb = bk * 256;
  {
    int g = t >> 2, ks = (t & 3) * 64;
    const short8* src = (const short8*)(H + (size_t)g * 64000 + kb + ks);
#pragma unroll
    for (int i = 0; i < 8; ++i) {
      short8 v = src[i];
      *(short8*)&Hs[g][ks + i * 8] = v;
    }
  }
  __syncthreads();

  int wv = t >> 6, lane = t & 63;
  int arow = lane & 15, kgrp = (lane >> 4) * 8;
  f32x4 acc0 = {0.f, 0.f, 0.f, 0.f};
  f32x4 acc1 = {0.f, 0.f, 0.f, 0.f};
  f32x4 acc2 = {0.f, 0.f, 0.f, 0.f};
  f32x4 acc3 = {0.f, 0.f, 0.f, 0.f};

  const float* wp = W + (size_t)(bo * 64 + wv * 16 + arow) * 64000 + kb + kgrp;
#pragma unroll
  for (int kstep = 0; kstep < 8; ++kstep) {
    f32x4 w0 = *(const f32x4*)(wp);
    f32x4 w1 = *(const f32x4*)(wp + 4);
    wp += 32;
    half8 a;
    a[0] = (_Float16)w0[0]; a[1] = (_Float16)w0[1];
    a[2] = (_Float16)w0[2]; a[3] = (_Float16)w0[3];
    a[4] = (_Float16)w1[0]; a[5] = (_Float16)w1[1];
    a[6] = (_Float16)w1[2]; a[7] = (_Float16)w1[3];
    int kk = kstep * 32 + kgrp;
    half8 b0 = *(const half8*)&Hs[arow][kk];
    half8 b1 = *(const half8*)&Hs[16 + arow][kk];
    half8 b2 = *(const half8*)&Hs[32 + arow][kk];
    half8 b3 = *(const half8*)&Hs[48 + arow][kk];
    acc0 = __builtin_amdgcn_mfma_f32_16x16x32_f16(a, b0, acc0, 0, 0, 0);
    acc1 = __builtin_amdgcn_mfma_f32_16x16x32_f16(a, b1, acc1, 0, 0, 0);
    acc2 = __builtin_amdgcn_mfma_f32_16x16x32_f16(a, b2, acc2, 0, 0, 0);
    acc3 = __builtin_amdgcn_mfma_f32_16x16x32_f16(a, b3, acc3, 0, 0, 0);
  }

  float* dst = r1p + (size_t)bk * 32768;
  int orow = bo * 64 + wv * 16 + (lane >> 4) * 4;
  int g = lane & 15;
#pragma unroll
  for (int reg = 0; reg < 4; ++reg) {
    dst[(orow + reg) * 64 + g]      = acc0[reg];
    dst[(orow + reg) * 64 + 16 + g] = acc1[reg];
    dst[(orow + reg) * 64 + 32 + g] = acc2[reg];
    dst[(orow + reg) * 64 + 48 + g] = acc3[reg];
  }
}

// reduce 250 partials, add bias, relu -> r1t[o][g]
__global__ void k_red(const float* __restrict__ r1p, const float* __restrict__ b,
                      float* __restrict__ r1t) {
  int i = blockIdx.x * 256 + threadIdx.x;  // 0..32767
  float s = 0.f;
#pragma unroll 5
  for (int p = 0; p < 250; ++p) s += r1p[(size_t)p * 32768 + i];
  int o = i >> 6;
  r1t[i] = fmaxf(s + b[o], 0.f);
}

__global__ void k_lin2(const float* __restrict__ r1t, const float* __restrict__ W,
                       const float* __restrict__ b, float* __restrict__ r2t) {
  int o = blockIdx.x, g = threadIdx.x;
  float acc = 0.f;
#pragma unroll 4
  for (int i = 0; i < 512; ++i) acc += r1t[i * 64 + g] * W[o * 512 + i];
  r2t[o * 64 + g] = fmaxf(acc + b[o], 0.f);
}

__global__ void k_lin3(const float* __restrict__ r2t, const float* __restrict__ W,
                       const float* __restrict__ b, float* __restrict__ out) {
  int o = blockIdx.x, g = threadIdx.x;
  float acc = 0.f;
#pragma unroll 4
  for (int i = 0; i < 512; ++i) acc += r2t[i * 64 + g] * W[o * 512 + i];
  out[g * 10 + o] = fmaxf(acc + b[o], 0.f);
}

// ---------------- launch ----------------

extern "C" void kernel_launch(void* const* d_in, const int* in_sizes, int n_in,
                              void* d_out, int out_size, void* d_ws, size_t ws_size,
                              hipStream_t stream) {
  const float* x    = (const float*)d_in[0];
  const int*   ei   = (const int*)d_in[1];
  const float* w1_1 = (const float*)d_in[3];  const float* b1_1 = (const float*)d_in[4];
  const float* w1_2 = (const float*)d_in[5];  const float* b1_2 = (const float*)d_in[6];
  const float* w1_3 = (const float*)d_in[7];  const float* b1_3 = (const float*)d_in[8];
  const float* w2_1 = (const float*)d_in[9];  const float* b2_1 = (const float*)d_in[10];
  const float* w2_2 = (const float*)d_in[11]; const float* b2_2 = (const float*)d_in[12];
  const float* w3_1 = (const float*)d_in[13]; const float* b3_1 = (const float*)d_in[14];
  const float* l1w  = (const float*)d_in[15]; const float* l1b  = (const float*)d_in[16];
  const float* l2w  = (const float*)d_in[17]; const float* l2b  = (const float*)d_in[18];
  const float* l3w  = (const float*)d_in[19]; const float* l3b  = (const float*)d_in[20];

  char* ws = (char*)d_ws;
  size_t off = 0;
  auto alloc = [&](size_t bytes) -> char* {
    char* p = ws + off;
    off += (bytes + 255) & ~(size_t)255;
    return p;
  };
  __half* A    = (__half*)alloc((size_t)NN * 64 * 2);
  __half* Bb   = (__half*)alloc((size_t)NN * 64 * 2);
  __half* C    = (__half*)alloc((size_t)NN * 64 * 2);
  __half* T1   = (__half*)alloc((size_t)NN * 64 * 2);
  __half* T2   = (__half*)alloc((size_t)NN * 64 * 2);
  int*   deg  = (int*)alloc(NN * 4);
  float* dis  = (float*)alloc(NN * 4);
  int*   rowp = (int*)alloc((NN + 1) * 4);
  int*   fillp= (int*)alloc(NN * 4);
  unsigned* edata = (unsigned*)alloc((size_t)ET * 4);
  float* t1s  = (float*)alloc(NN * 4);
  float* g2s  = (float*)alloc(NN * 4);
  float* r1t  = (float*)alloc(512 * 64 * 4);
  float* r2t  = (float*)alloc(512 * 64 * 4);
  int*   bsum = (int*)alloc(256 * 4);
  int*   boff = (int*)alloc(256 * 4);
  float* r1p  = (float*)alloc((size_t)250 * 32768 * 4);
  float* wt11 = (float*)alloc(192 * 4);
  __half* wtT12 = (__half*)alloc(12288 * 2);
  __half* wtT13 = (__half*)alloc(12288 * 2);
  __half* wtT21 = (__half*)alloc(12288 * 2);
  __half* wtT22 = (__half*)alloc(12288 * 2);
  __half* wtT31 = (__half*)alloc(12288 * 2);

  hipMemsetAsync(deg, 0, NN * 4, stream);

  k_deg<<<ET / 256, 256, 0, stream>>>(ei, deg);
  k_scan1<<<NN / 256, 256, 0, stream>>>(deg, dis, rowp, bsum);
  k_scan2<<<1, 256, 0, stream>>>(bsum, boff);
  k_scan3<<<NN / 256, 256, 0, stream>>>(rowp, boff, fillp);
  k_fill<<<ET / 256, 256, 0, stream>>>(ei, dis, fillp, edata);

  k_wx1<<<1, 64, 0, stream>>>(w1_1, wt11);
  k_wxt<<<48, 256, 0, stream>>>(w1_2, wtT12);
  k_wxt<<<48, 256, 0, stream>>>(w1_3, wtT13);
  k_wxt<<<48, 256, 0, stream>>>(w2_1, wtT21);
  k_wxt<<<48, 256, 0, stream>>>(w2_2, wtT22);
  k_wxt<<<48, 256, 0, stream>>>(w3_1, wtT31);

  // layer 1 (1 -> 64 channels)
  k_prop_s<<<NN / 256, 256, 0, stream>>>(x, rowp, edata, t1s);
  k_prop_s<<<NN / 256, 256, 0, stream>>>(t1s, rowp, edata, g2s);
  k_layer1<<<NN / 4, 256, 0, stream>>>(x, t1s, g2s, wt11, b1_1, A);

  auto cheb = [&](const __half* in, const __half* WtT, const float* bias,
                  int relu_f, const __half* res, __half* out) {
    k_prop64<<<NN / 2, 256, 0, stream>>>(in, rowp, edata, T1);
    k_prop64<<<NN / 2, 256, 0, stream>>>(T1, rowp, edata, T2);
    if (relu_f)
      k_mat64<1, 0><<<NN / 256, 256, 0, stream>>>(in, T1, T2, WtT, bias, nullptr, out);
    else
      k_mat64<0, 1><<<NN / 256, 256, 0, stream>>>(in, T1, T2, WtT, bias, res, out);
  };

  cheb(A,  wtT12, b1_2, 1, nullptr, Bb);
  cheb(Bb, wtT13, b1_3, 0, A,       C);
  cheb(C,  wtT21, b2_1, 1, nullptr, A);
  cheb(A,  wtT22, b2_2, 0, C,       Bb);
  cheb(Bb, wtT31, b3_1, 1, nullptr, C);   // final H in C

  k_lin1<<<2000, 256, 0, stream>>>(C, l1w, r1p);
  k_red<<<32768 / 256, 256, 0, stream>>>(r1p, l1b, r1t);
  k_lin2<<<512, 64, 0, stream>>>(r1t, l2w, l2b, r2t);
  k_lin3<<<10, 64, 0, stream>>>(r2t, l3w, l3b, (float*)d_out);
}

// Round 10
// 572.804 us; speedup vs baseline: 1.5899x; 1.4246x over previous
//
#include <hip/hip_runtime.h>
#include <hip/hip_fp16.h>

#define NN 64000
#define ET 1024000

typedef __attribute__((ext_vector_type(8))) short short8;
typedef __attribute__((ext_vector_type(8))) _Float16 half8;
typedef __attribute__((ext_vector_type(4))) float f32x4;

__device__ inline float h2f(__half h) { return __half2float(h); }
__device__ inline float dec_w(unsigned p) {
  return __half2float(__ushort_as_half((unsigned short)(p >> 16)));
}

// ---------------- graph build (single-region CSR) ----------------

__global__ void k_deg(const int* __restrict__ ei, int* __restrict__ deg) {
  int e = blockIdx.x * 256 + threadIdx.x;
  if (e < ET) atomicAdd(&deg[ei[e]], 1);
}

__global__ void k_scan1(const int* __restrict__ deg, float* __restrict__ dis,
                        int* __restrict__ rowp, int* __restrict__ bsum) {
  __shared__ int buf[256];
  int t = threadIdx.x;
  int idx = blockIdx.x * 256 + t;
  int v = deg[idx];
  dis[idx] = v > 0 ? rsqrtf((float)v) : 0.f;
  buf[t] = v;
  __syncthreads();
  for (int off = 1; off < 256; off <<= 1) {
    int x = (t >= off) ? buf[t - off] : 0;
    __syncthreads();
    buf[t] += x;
    __syncthreads();
  }
  rowp[idx] = buf[t] - v;
  if (t == 255) bsum[blockIdx.x] = buf[t];
}

__global__ void k_scan2(const int* __restrict__ bsum, int* __restrict__ boff) {
  __shared__ int buf[256];
  int t = threadIdx.x;
  int v = (t < 250) ? bsum[t] : 0;
  buf[t] = v;
  __syncthreads();
  for (int off = 1; off < 256; off <<= 1) {
    int x = (t >= off) ? buf[t - off] : 0;
    __syncthreads();
    buf[t] += x;
    __syncthreads();
  }
  if (t < 250) boff[t] = buf[t] - v;
}

__global__ void k_scan3(int* __restrict__ rowp, const int* __restrict__ boff,
                        int* __restrict__ fillp) {
  int idx = blockIdx.x * 256 + threadIdx.x;
  int v = rowp[idx] + boff[blockIdx.x];
  rowp[idx] = v;
  fillp[idx] = v;
  if (idx == 0) rowp[NN] = ET;
}

// packed edge record: low16 = src node, high16 = f16 norm
__global__ void k_fill(const int* __restrict__ ei, const float* __restrict__ dis,
                       int* __restrict__ fillp, unsigned* __restrict__ edata) {
  int e = blockIdx.x * 256 + threadIdx.x;
  if (e >= ET) return;
  int s = ei[e];
  int d = ei[ET + e];
  float nrm = -dis[s] * dis[d];
  unsigned packed = (unsigned)s |
      ((unsigned)__half_as_ushort(__float2half(nrm)) << 16);
  int p = atomicAdd(&fillp[d], 1);
  edata[p] = packed;
}

// ---------------- Chebyshev weight fold ----------------
// out = h*W0 + T1*W1 + (2*L*T1 - h)*W2 == h*(W0-W2) + T1*W1 + (L*T1)*(2*W2)

// layer-1 weights [3][1][64] -> folded f32
__global__ void k_wx1(const float* __restrict__ s, float* __restrict__ d) {
  int f = threadIdx.x;  // 64
  d[f]       = s[f] - s[128 + f];
  d[64 + f]  = s[64 + f];
  d[128 + f] = 2.f * s[128 + f];
}

// 5 weight sets [3][64k][64f] -> folded fp16 TRANSPOSED [3][64f][64k]
struct WT5 { const float* s0; const float* s1; const float* s2;
             const float* s3; const float* s4;
             __half* d0; __half* d1; __half* d2; __half* d3; __half* d4; };

__global__ void k_wxt5(WT5 a) {
  int b = blockIdx.x;
  int set = b / 48;
  const float* s; __half* d;
  switch (set) {
    case 0: s = a.s0; d = a.d0; break;
    case 1: s = a.s1; d = a.d1; break;
    case 2: s = a.s2; d = a.d2; break;
    case 3: s = a.s3; d = a.d3; break;
    default: s = a.s4; d = a.d4; break;
  }
  int i = (b - set * 48) * 256 + threadIdx.x;   // 0..12287
  int arr = i >> 12, rem = i & 4095, f = rem >> 6, k = rem & 63;
  float s0 = s[k * 64 + f];
  float s1 = s[4096 + k * 64 + f];
  float s2 = s[8192 + k * 64 + f];
  float v = arr == 0 ? s0 - s2 : (arr == 1 ? s1 : 2.f * s2);
  d[i] = __float2half(v);
}

// ---------------- scalar (1-channel) plain prop for layer 1 (f32) ----------

__global__ void k_prop_s(const float* __restrict__ in, const int* __restrict__ rowp,
                         const unsigned* __restrict__ edata, float* __restrict__ out) {
  int n = blockIdx.x * 256 + threadIdx.x;
  if (n >= NN) return;
  int s = rowp[n], e = rowp[n + 1];
  float acc = 0.f;
  int j = s;
  for (; j + 4 <= e; j += 4) {
    unsigned e0 = edata[j], e1 = edata[j + 1], e2 = edata[j + 2], e3 = edata[j + 3];
    acc += in[e0 & 0xFFFFu] * dec_w(e0) + in[e1 & 0xFFFFu] * dec_w(e1) +
           in[e2 & 0xFFFFu] * dec_w(e2) + in[e3 & 0xFFFFu] * dec_w(e3);
  }
  for (; j < e; ++j) {
    unsigned e0 = edata[j];
    acc += in[e0 & 0xFFFFu] * dec_w(e0);
  }
  out[n] = acc;
}

__global__ void k_layer1(const float* __restrict__ x, const float* __restrict__ t1,
                         const float* __restrict__ g2, const float* __restrict__ w,
                         const float* __restrict__ b, __half* __restrict__ out) {
  int t = threadIdx.x;
  int node = blockIdx.x * 4 + (t >> 6);
  int f = t & 63;
  float v = x[node] * w[f] + t1[node] * w[64 + f] + g2[node] * w[128 + f] + b[f];
  out[(size_t)node * 64 + f] = __float2half(fmaxf(v, 0.f));
}

// ---------------- 64-channel plain prop (r7 winner): wave/node, lane=feat --

__global__ __launch_bounds__(256) void k_prop64(const __half* __restrict__ in,
    const int* __restrict__ rowp, const unsigned* __restrict__ edata,
    __half* __restrict__ out) {
  int node = __builtin_amdgcn_readfirstlane(blockIdx.x * 4 + (threadIdx.x >> 6));
  int f = threadIdx.x & 63;
  int s = rowp[node], e = rowp[node + 1];
  float a[16];
#pragma unroll
  for (int i = 0; i < 16; ++i) a[i] = 0.f;
  int j = s;
  for (; j + 16 <= e; j += 16) {
    unsigned ed[16];
#pragma unroll
    for (int i = 0; i < 16; ++i) ed[i] = edata[j + i];
    float v[16];
#pragma unroll
    for (int i = 0; i < 16; ++i) v[i] = h2f(in[(size_t)(ed[i] & 0xFFFFu) * 64 + f]);
#pragma unroll
    for (int i = 0; i < 16; ++i) a[i] += v[i] * dec_w(ed[i]);
  }
  for (; j + 8 <= e; j += 8) {
    unsigned ed[8];
#pragma unroll
    for (int i = 0; i < 8; ++i) ed[i] = edata[j + i];
    float v[8];
#pragma unroll
    for (int i = 0; i < 8; ++i) v[i] = h2f(in[(size_t)(ed[i] & 0xFFFFu) * 64 + f]);
#pragma unroll
    for (int i = 0; i < 8; ++i) a[i] += v[i] * dec_w(ed[i]);
  }
  for (; j + 4 <= e; j += 4) {
    unsigned ed[4];
#pragma unroll
    for (int i = 0; i < 4; ++i) ed[i] = edata[j + i];
    float v[4];
#pragma unroll
    for (int i = 0; i < 4; ++i) v[i] = h2f(in[(size_t)(ed[i] & 0xFFFFu) * 64 + f]);
#pragma unroll
    for (int i = 0; i < 4; ++i) a[i] += v[i] * dec_w(ed[i]);
  }
  for (; j < e; ++j) {
    unsigned e0 = edata[j];
    a[0] += h2f(in[(size_t)(e0 & 0xFFFFu) * 64 + f]) * dec_w(e0);
  }
#pragma unroll
  for (int i = 0; i < 8; ++i) a[i] += a[i + 8];
#pragma unroll
  for (int i = 0; i < 4; ++i) a[i] += a[i + 4];
  float acc = (a[0] + a[1]) + (a[2] + a[3]);
  out[(size_t)node * 64 + f] = __float2half(acc);
}

// ------- fused cheb matmul via MFMA: out = [T0|T1|G2] @ Wcat' (+b, relu/res)

template<int RELU, int RES>
__global__ __launch_bounds__(256) void k_mat64(
    const __half* __restrict__ T0, const __half* __restrict__ T1,
    const __half* __restrict__ T2, const __half* __restrict__ wtT,  // [3][64f][64k]
    const float* __restrict__ bias, const __half* __restrict__ res,
    __half* __restrict__ out) {
  int t = threadIdx.x;
  int wv = t >> 6, lane = t & 63;
  int node0 = blockIdx.x * 256 + wv * 64;
  int l15 = lane & 15, kg = (lane >> 4) * 8;
  f32x4 acc[4][4];
#pragma unroll
  for (int mt = 0; mt < 4; ++mt)
#pragma unroll
    for (int nt = 0; nt < 4; ++nt) acc[mt][nt] = {0.f, 0.f, 0.f, 0.f};

  const __half* Ts[3] = {T0, T1, T2};
#pragma unroll
  for (int arr = 0; arr < 3; ++arr) {
    const __half* T = Ts[arr];
    const __half* wb = wtT + arr * 4096;
#pragma unroll
    for (int ks = 0; ks < 2; ++ks) {
      int k0 = ks * 32 + kg;
      half8 b[4];
#pragma unroll
      for (int nt = 0; nt < 4; ++nt)
        b[nt] = *(const half8*)&wb[(nt * 16 + l15) * 64 + k0];
#pragma unroll
      for (int mt = 0; mt < 4; ++mt) {
        half8 a = *(const half8*)&T[(size_t)(node0 + mt * 16 + l15) * 64 + k0];
#pragma unroll
        for (int nt = 0; nt < 4; ++nt)
          acc[mt][nt] = __builtin_amdgcn_mfma_f32_16x16x32_f16(a, b[nt], acc[mt][nt], 0, 0, 0);
      }
    }
  }

  int row0 = (lane >> 4) * 4;
#pragma unroll
  for (int mt = 0; mt < 4; ++mt) {
#pragma unroll
    for (int nt = 0; nt < 4; ++nt) {
      int fcol = nt * 16 + l15;
      float bv = bias[fcol];
#pragma unroll
      for (int reg = 0; reg < 4; ++reg) {
        int node = node0 + mt * 16 + row0 + reg;
        float v = acc[mt][nt][reg] + bv;
        if (RES) v += h2f(res[(size_t)node * 64 + fcol]);
        if (RELU) v = fmaxf(v, 0.f);
        out[(size_t)node * 64 + fcol] = __float2half(v);
      }
    }
  }
}

// ---------------- readout: MFMA lin1, 125 k-splits x 512 k ----------------

__global__ __launch_bounds__(256) void k_lin1(const __half* __restrict__ H,
    const float* __restrict__ W, float* __restrict__ r1p) {
  __shared__ _Float16 Hs[64][520];  // 66.5 KB
  int t = threadIdx.x;
  int bo = blockIdx.x & 7;
  int bk = blockIdx.x >> 3;      // 0..124
  int kb = bk * 512;
  {
    int g = t >> 2, ks = (t & 3) * 128;
    const short8* src = (const short8*)(H + (size_t)g * 64000 + kb + ks);
#pragma unroll
    for (int i = 0; i < 16; ++i) {
      short8 v = src[i];
      *(short8*)&Hs[g][ks + i * 8] = v;
    }
  }
  __syncthreads();

  int wv = t >> 6, lane = t & 63;
  int arow = lane & 15, kgrp = (lane >> 4) * 8;
  f32x4 acc0 = {0.f, 0.f, 0.f, 0.f};
  f32x4 acc1 = {0.f, 0.f, 0.f, 0.f};
  f32x4 acc2 = {0.f, 0.f, 0.f, 0.f};
  f32x4 acc3 = {0.f, 0.f, 0.f, 0.f};

  const float* wp = W + (size_t)(bo * 64 + wv * 16 + arow) * 64000 + kb + kgrp;
#pragma unroll
  for (int kstep = 0; kstep < 16; ++kstep) {
    f32x4 w0 = *(const f32x4*)(wp);
    f32x4 w1 = *(const f32x4*)(wp + 4);
    wp += 32;
    half8 a;
    a[0] = (_Float16)w0[0]; a[1] = (_Float16)w0[1];
    a[2] = (_Float16)w0[2]; a[3] = (_Float16)w0[3];
    a[4] = (_Float16)w1[0]; a[5] = (_Float16)w1[1];
    a[6] = (_Float16)w1[2]; a[7] = (_Float16)w1[3];
    int kk = kstep * 32 + kgrp;
    half8 b0 = *(const half8*)&Hs[arow][kk];
    half8 b1 = *(const half8*)&Hs[16 + arow][kk];
    half8 b2 = *(const half8*)&Hs[32 + arow][kk];
    half8 b3 = *(const half8*)&Hs[48 + arow][kk];
    acc0 = __builtin_amdgcn_mfma_f32_16x16x32_f16(a, b0, acc0, 0, 0, 0);
    acc1 = __builtin_amdgcn_mfma_f32_16x16x32_f16(a, b1, acc1, 0, 0, 0);
    acc2 = __builtin_amdgcn_mfma_f32_16x16x32_f16(a, b2, acc2, 0, 0, 0);
    acc3 = __builtin_amdgcn_mfma_f32_16x16x32_f16(a, b3, acc3, 0, 0, 0);
  }

  float* dst = r1p + (size_t)bk * 32768;
  int orow = bo * 64 + wv * 16 + (lane >> 4) * 4;
  int g = lane & 15;
#pragma unroll
  for (int reg = 0; reg < 4; ++reg) {
    dst[(orow + reg) * 64 + g]      = acc0[reg];
    dst[(orow + reg) * 64 + 16 + g] = acc1[reg];
    dst[(orow + reg) * 64 + 32 + g] = acc2[reg];
    dst[(orow + reg) * 64 + 48 + g] = acc3[reg];
  }
}

// reduce 125 partials, add bias, relu -> r1t[o][g]
__global__ void k_red(const float* __restrict__ r1p, const float* __restrict__ b,
                      float* __restrict__ r1t) {
  int i = blockIdx.x * 256 + threadIdx.x;  // 0..32767
  float s = 0.f;
#pragma unroll 5
  for (int p = 0; p < 125; ++p) s += r1p[(size_t)p * 32768 + i];
  int o = i >> 6;
  r1t[i] = fmaxf(s + b[o], 0.f);
}

__global__ void k_lin2(const float* __restrict__ r1t, const float* __restrict__ W,
                       const float* __restrict__ b, float* __restrict__ r2t) {
  int o = blockIdx.x, g = threadIdx.x;
  float acc = 0.f;
#pragma unroll 4
  for (int i = 0; i < 512; ++i) acc += r1t[i * 64 + g] * W[o * 512 + i];
  r2t[o * 64 + g] = fmaxf(acc + b[o], 0.f);
}

__global__ void k_lin3(const float* __restrict__ r2t, const float* __restrict__ W,
                       const float* __restrict__ b, float* __restrict__ out) {
  int o = blockIdx.x, g = threadIdx.x;
  float acc = 0.f;
#pragma unroll 4
  for (int i = 0; i < 512; ++i) acc += r2t[i * 64 + g] * W[o * 512 + i];
  out[g * 10 + o] = fmaxf(acc + b[o], 0.f);
}

// ---------------- launch ----------------

extern "C" void kernel_launch(void* const* d_in, const int* in_sizes, int n_in,
                              void* d_out, int out_size, void* d_ws, size_t ws_size,
                              hipStream_t stream) {
  const float* x    = (const float*)d_in[0];
  const int*   ei   = (const int*)d_in[1];
  const float* w1_1 = (const float*)d_in[3];  const float* b1_1 = (const float*)d_in[4];
  const float* w1_2 = (const float*)d_in[5];  const float* b1_2 = (const float*)d_in[6];
  const float* w1_3 = (const float*)d_in[7];  const float* b1_3 = (const float*)d_in[8];
  const float* w2_1 = (const float*)d_in[9];  const float* b2_1 = (const float*)d_in[10];
  const float* w2_2 = (const float*)d_in[11]; const float* b2_2 = (const float*)d_in[12];
  const float* w3_1 = (const float*)d_in[13]; const float* b3_1 = (const float*)d_in[14];
  const float* l1w  = (const float*)d_in[15]; const float* l1b  = (const float*)d_in[16];
  const float* l2w  = (const float*)d_in[17]; const float* l2b  = (const float*)d_in[18];
  const float* l3w  = (const float*)d_in[19]; const float* l3b  = (const float*)d_in[20];

  char* ws = (char*)d_ws;
  size_t off = 0;
  auto alloc = [&](size_t bytes) -> char* {
    char* p = ws + off;
    off += (bytes + 255) & ~(size_t)255;
    return p;
  };
  __half* A    = (__half*)alloc((size_t)NN * 64 * 2);
  __half* Bb   = (__half*)alloc((size_t)NN * 64 * 2);
  __half* C    = (__half*)alloc((size_t)NN * 64 * 2);
  __half* T1   = (__half*)alloc((size_t)NN * 64 * 2);
  __half* T2   = (__half*)alloc((size_t)NN * 64 * 2);
  int*   deg  = (int*)alloc(NN * 4);
  float* dis  = (float*)alloc(NN * 4);
  int*   rowp = (int*)alloc((NN + 1) * 4);
  int*   fillp= (int*)alloc(NN * 4);
  unsigned* edata = (unsigned*)alloc((size_t)ET * 4);
  float* t1s  = (float*)alloc(NN * 4);
  float* g2s  = (float*)alloc(NN * 4);
  float* r1t  = (float*)alloc(512 * 64 * 4);
  float* r2t  = (float*)alloc(512 * 64 * 4);
  int*   bsum = (int*)alloc(256 * 4);
  int*   boff = (int*)alloc(256 * 4);
  float* r1p  = (float*)alloc((size_t)125 * 32768 * 4);
  float* wt11 = (float*)alloc(192 * 4);
  __half* wtT12 = (__half*)alloc(12288 * 2);
  __half* wtT13 = (__half*)alloc(12288 * 2);
  __half* wtT21 = (__half*)alloc(12288 * 2);
  __half* wtT22 = (__half*)alloc(12288 * 2);
  __half* wtT31 = (__half*)alloc(12288 * 2);

  hipMemsetAsync(deg, 0, NN * 4, stream);

  k_deg<<<ET / 256, 256, 0, stream>>>(ei, deg);
  k_scan1<<<NN / 256, 256, 0, stream>>>(deg, dis, rowp, bsum);
  k_scan2<<<1, 256, 0, stream>>>(bsum, boff);
  k_scan3<<<NN / 256, 256, 0, stream>>>(rowp, boff, fillp);
  k_fill<<<ET / 256, 256, 0, stream>>>(ei, dis, fillp, edata);

  k_wx1<<<1, 64, 0, stream>>>(w1_1, wt11);
  WT5 wt5{w1_2, w1_3, w2_1, w2_2, w3_1, wtT12, wtT13, wtT21, wtT22, wtT31};
  k_wxt5<<<240, 256, 0, stream>>>(wt5);

  // layer 1 (1 -> 64 channels)
  k_prop_s<<<NN / 256, 256, 0, stream>>>(x, rowp, edata, t1s);
  k_prop_s<<<NN / 256, 256, 0, stream>>>(t1s, rowp, edata, g2s);
  k_layer1<<<NN / 4, 256, 0, stream>>>(x, t1s, g2s, wt11, b1_1, A);

  auto cheb = [&](const __half* in, const __half* WtT, const float* bias,
                  int relu_f, const __half* res, __half* out) {
    k_prop64<<<NN / 4, 256, 0, stream>>>(in, rowp, edata, T1);
    k_prop64<<<NN / 4, 256, 0, stream>>>(T1, rowp, edata, T2);
    if (relu_f)
      k_mat64<1, 0><<<NN / 256, 256, 0, stream>>>(in, T1, T2, WtT, bias, nullptr, out);
    else
      k_mat64<0, 1><<<NN / 256, 256, 0, stream>>>(in, T1, T2, WtT, bias, res, out);
  };

  cheb(A,  wtT12, b1_2, 1, nullptr, Bb);
  cheb(Bb, wtT13, b1_3, 0, A,       C);
  cheb(C,  wtT21, b2_1, 1, nullptr, A);
  cheb(A,  wtT22, b2_2, 0, C,       Bb);
  cheb(Bb, wtT31, b3_1, 1, nullptr, C);   // final H in C

  k_lin1<<<1000, 256, 0, stream>>>(C, l1w, r1p);
  k_red<<<32768 / 256, 256, 0, stream>>>(r1p, l1b, r1t);
  k_lin2<<<512, 64, 0, stream>>>(r1t, l2w, l2b, r2t);
  k_lin3<<<10, 64, 0, stream>>>(r2t, l3w, l3b, (float*)d_out);
}